// Round 8
// baseline (172.105 us; speedup 1.0000x reference)
//
#include <hip/hip_runtime.h>

#define NBINS 229
#define OUTF  88
#define MODEL 128
#define WSZ   30
#define WIN   61
#define TLEN  1024
#define BT    4096

#define NC1 648      // gemm1 real cols
#define NP1 704      // gemm1 padded cols (11*64)
#define KP1 256      // gemm1 padded K (8*32); real 229
#define C1LD 560     // C1 stores gemm1 cols [88,648) -> stride 560

typedef short bf16x8 __attribute__((ext_vector_type(8)));
typedef float f32x4 __attribute__((ext_vector_type(4)));
typedef unsigned short ushort_t;

__device__ __forceinline__ float sigmoid_f(float x) {
    return __builtin_amdgcn_rcpf(1.f + __expf(-x));
}
__device__ __forceinline__ ushort_t f2bf(float f) {
    unsigned u = __float_as_uint(f);
    return (ushort_t)((u + 0x7fffu + ((u >> 16) & 1u)) >> 16);
}
// dot of 8 bf16 weights (packed in uint4) with 8 fp32 x values
__device__ __forceinline__ float dot8(const ushort_t* wp, float4 xa, float4 xb) {
    uint4 u = *(const uint4*)wp;
    float s;
    s  = __uint_as_float(u.x << 16) * xa.x + __uint_as_float(u.x & 0xffff0000u) * xa.y;
    s += __uint_as_float(u.y << 16) * xa.z + __uint_as_float(u.y & 0xffff0000u) * xa.w;
    s += __uint_as_float(u.z << 16) * xb.x + __uint_as_float(u.z & 0xffff0000u) * xb.y;
    s += __uint_as_float(u.w << 16) * xb.z + __uint_as_float(u.w & 0xffff0000u) * xb.w;
    return s;
}

// ---------------------------------------------------------------------------
// prep: build bf16 GEMM operands + fp32 biases + sv sums.
// B1b[n][k] (n-major, 704x256) column map (n):
//   [  0, 88) Wf[k][n]          [ 88,216) Wao[k][n-88]
//   [216,344) Wao[k+229][n-216] [344,472) Wac[k+176][n-344]
//   [472,560) Wl1[k][n-472]     [560,648) Wlc[k+176][n-560]
// B2b[n][k] (256x192): [0,128) Wac[k][n]; [128,216) Wlc[k][n-128]; pad 0
// specB[4096][256] bf16 row-major (k>=229 zero)
// bias1: [0,88)=bf, [88,216)=bao, else 0 ; bias2: [0,128)=bac, else 0
// sv[0]=sum(vo), sv[1]=sum(vc)
// ---------------------------------------------------------------------------
#define PREP_BLOCKS 1925

__global__ __launch_bounds__(256) void prep_kernel(
    const float* __restrict__ Wf,  const float* __restrict__ bfr,
    const float* __restrict__ Wao, const float* __restrict__ bao,
    const float* __restrict__ Wl1,
    const float* __restrict__ Wac, const float* __restrict__ bac,
    const float* __restrict__ Wlc,
    const float* __restrict__ spec,
    const float* __restrict__ vo, const float* __restrict__ vc,
    ushort_t* __restrict__ B1b, ushort_t* __restrict__ B2b,
    ushort_t* __restrict__ specB,
    float* __restrict__ bias1, float* __restrict__ bias2,
    float* __restrict__ sv)
{
    __shared__ float red[4];
    const int b = blockIdx.x;
    if (b < 704) {                                  // B1b
        int idx = b * 256 + threadIdx.x;
        int n = idx >> 8, k = idx & 255;
        float v = 0.f;
        if (k < NBINS && n < NC1) {
            if (n < 88)       v = Wf[k * 88 + n];
            else if (n < 216) v = Wao[k * MODEL + (n - 88)];
            else if (n < 344) v = Wao[(k + NBINS) * MODEL + (n - 216)];
            else if (n < 472) v = Wac[(k + 176) * MODEL + (n - 344)];
            else if (n < 560) v = Wl1[k * 88 + (n - 472)];
            else              v = Wlc[(k + 176) * 88 + (n - 560)];
        }
        B1b[idx] = f2bf(v);
    } else if (b < 896) {                           // B2b
        int idx = (b - 704) * 256 + threadIdx.x;
        int n = idx / 192, k = idx - n * 192;
        float v = 0.f;
        if (k < 176 && n < 216)
            v = (n < 128) ? Wac[k * MODEL + n] : Wlc[k * 88 + (n - 128)];
        B2b[idx] = f2bf(v);
    } else if (b < 1920) {                          // specB, 4 elems/thread
        int idx = (b - 896) * 256 + threadIdx.x;
        int r = idx >> 6, k4 = (idx & 63) * 4;
        const float* sp = spec + (size_t)r * NBINS;
        ushort4 o;
        o.x = (k4 + 0 < NBINS) ? f2bf(sp[k4 + 0]) : (ushort_t)0;
        o.y = (k4 + 1 < NBINS) ? f2bf(sp[k4 + 1]) : (ushort_t)0;
        o.z = (k4 + 2 < NBINS) ? f2bf(sp[k4 + 2]) : (ushort_t)0;
        o.w = (k4 + 3 < NBINS) ? f2bf(sp[k4 + 3]) : (ushort_t)0;
        *(ushort4*)&specB[(size_t)r * 256 + k4] = o;
    } else if (b < 1924) {                          // biases
        int idx = (b - 1920) * 256 + threadIdx.x;
        if (idx < 704)
            bias1[idx] = (idx < 88) ? bfr[idx] : (idx < 216 ? bao[idx - 88] : 0.f);
        else if (idx < 960) {
            int n = idx - 704;
            bias2[n] = (n < 128) ? bac[n] : 0.f;
        }
    } else {                                        // sv sums
        int wid = threadIdx.x >> 6, lane = threadIdx.x & 63;
        const float* vp = (wid < 2) ? vo : vc;
        float val = vp[(wid & 1) * 64 + lane];
#pragma unroll
        for (int m = 32; m; m >>= 1) val += __shfl_xor(val, m, 64);
        if (lane == 0) red[wid] = val;
        __syncthreads();
        if (threadIdx.x == 0) {
            sv[0] = red[0] + red[1];
            sv[1] = red[2] + red[3];
        }
    }
}

// ---------------------------------------------------------------------------
// MFMA bf16 GEMM, no LDS: A/B fragments stream from global (L2-resident B).
// Block = 256 thr (4 waves); wave tile = (MT*16)m x 64n.
// XCD swizzle: e=flat&7 -> rows [512e,512e+512) on XCD e.
// Epilogue: val=acc+bias[n]; cols [sclo,schi) -> exp(2*val) (pre-factored
// attention energies); n>=cskip -> C[m*ldc+n-cskip]; n<cskip -> feat fp32.
// ---------------------------------------------------------------------------
template<int MT, int KITER, int RTS>
__global__ __launch_bounds__(256) void gemm_mfma(
    const ushort_t* __restrict__ Ab, int lka,
    const ushort_t* __restrict__ Bb,
    const float* __restrict__ bias,
    float* __restrict__ C, int ldc, int Nc, int cskip, int sclo, int schi,
    float* __restrict__ feat_out)
{
    const int tid = threadIdx.x;
    const int wv = tid >> 6, ln = tid & 63;
    const int l15 = ln & 15, qd = ln >> 4;
    const int flat = blockIdx.y * gridDim.x + blockIdx.x;
    const int e = flat & 7, kf = flat >> 3;
    const int rb = (e * (1 << RTS) + (kf & ((1 << RTS) - 1))) * (MT * 64);
    const int cb = (kf >> RTS) * 64;
    const int lkb = KITER * 32;

    const ushort_t* ap[MT];
#pragma unroll
    for (int mt = 0; mt < MT; mt++)
        ap[mt] = Ab + (size_t)(rb + wv * MT * 16 + mt * 16 + l15) * lka + qd * 8;
    const ushort_t* bp[4];
#pragma unroll
    for (int nt = 0; nt < 4; nt++)
        bp[nt] = Bb + (size_t)(cb + nt * 16 + l15) * lkb + qd * 8;

    f32x4 acc[MT][4];
#pragma unroll
    for (int mt = 0; mt < MT; mt++)
#pragma unroll
        for (int nt = 0; nt < 4; nt++)
            acc[mt][nt] = (f32x4){0.f, 0.f, 0.f, 0.f};

    bf16x8 af[MT], bfv[4];
#pragma unroll
    for (int mt = 0; mt < MT; mt++) af[mt] = *(const bf16x8*)ap[mt];
#pragma unroll
    for (int nt = 0; nt < 4; nt++) bfv[nt] = *(const bf16x8*)bp[nt];

    for (int it = 0; it < KITER; it++) {
        bf16x8 an[MT], bn[4];
        const int nk = (it + 1 < KITER) ? (it + 1) * 32 : 0;
#pragma unroll
        for (int mt = 0; mt < MT; mt++) an[mt] = *(const bf16x8*)(ap[mt] + nk);
#pragma unroll
        for (int nt = 0; nt < 4; nt++) bn[nt] = *(const bf16x8*)(bp[nt] + nk);
#pragma unroll
        for (int mt = 0; mt < MT; mt++)
#pragma unroll
            for (int nt = 0; nt < 4; nt++)
                acc[mt][nt] = __builtin_amdgcn_mfma_f32_16x16x32_bf16(
                    af[mt], bfv[nt], acc[mt][nt], 0, 0, 0);
#pragma unroll
        for (int mt = 0; mt < MT; mt++) af[mt] = an[mt];
#pragma unroll
        for (int nt = 0; nt < 4; nt++) bfv[nt] = bn[nt];
    }

#pragma unroll
    for (int mt = 0; mt < MT; mt++) {
        const int mbase = rb + wv * MT * 16 + mt * 16 + qd * 4;
#pragma unroll
        for (int nt = 0; nt < 4; nt++) {
            const int n = cb + nt * 16 + l15;
            if (n < Nc) {
                const float bn = bias[n];
                const bool sc = (n >= sclo && n < schi);
#pragma unroll
                for (int r = 0; r < 4; r++) {
                    const int m = mbase + r;
                    float val = acc[mt][nt][r] + bn;
                    float sval = sc ? __expf(val + val) : val;
                    if (n >= cskip) C[(size_t)m * ldc + (n - cskip)] = sval;
                    else if (feat_out) feat_out[(size_t)m * 88 + n] = val;
                }
            }
        }
    }
}

// ---------------------------------------------------------------------------
// Fused attention1 + per-row gemm2 + attention2. One wave per position,
// 8 positions per 512-thread block, XCD-swizzled.
// Phase A: onset attention (EH_o s_loads, EP_o in LDS) -> onset_pred ->
//          x[s]=[feat,onset] in LDS.
// Phase B: stage EP_c into the same LDS buffer (overlaps matvec);
//          matvec x[s] @ B2b -> EH_c=exp(2(h_c+bac)) and linx, both in LDS.
// Phase C: combine attention (EH_c LDS broadcasts, EP_c in LDS) -> frame.
// ---------------------------------------------------------------------------
#define PST 132

__global__ __launch_bounds__(512) void attn_fused(
    const float* __restrict__ EH_o,   // C1 col 0   (exp'd, stride C1LD)
    const float* __restrict__ EP_o,   // C1 col 128 (exp'd)
    const float* __restrict__ EP_c,   // C1 col 256 (exp'd)
    const float* __restrict__ Rm,     // C1 col 384
    const float* __restrict__ Qm,     // C1 col 472
    const float* __restrict__ vo, const float* __restrict__ vc,
    const float* __restrict__ svp,
    const float* __restrict__ bl1, const float* __restrict__ blc,
    const float* __restrict__ bias2,
    const ushort_t* __restrict__ W2,  // B2b [256][192] bf16 n-major
    const float* __restrict__ feat,   // out4 [BT][88] fp32
    float* __restrict__ a_o, float* __restrict__ onset,
    float* __restrict__ a_c, float* __restrict__ frame)
{
    __shared__ float Pl[68 * PST];    // 35,904 B (EP_o, then EP_c)
    __shared__ float xl[8][176];      //  5,632 B
    __shared__ float EHl[8][128];     //  4,096 B
    __shared__ float lxl[8][88];      //  2,816 B

    const int tid = threadIdx.x;
    const int s0 = ((blockIdx.x & 7) * 64 + (blockIdx.x >> 3)) * 8;
    const int t0 = s0 & (TLEN - 1);
    const int q = tid >> 6;
    const int w = tid & 63;
    const int s = s0 + q;
    const int su = __builtin_amdgcn_readfirstlane(s);
    const bool inner = (t0 >= 32 && t0 <= 984);

    // ---- stage EP_o + load feat into x ----
    for (int i = tid; i < 68 * 32; i += 512) {
        int j = i >> 5, d4 = (i & 31) * 4;
        int tg = t0 + j - WSZ;
        float4 v = {1.f, 1.f, 1.f, 1.f};          // pad = exp(0)
        if ((unsigned)tg < (unsigned)TLEN)
            v = *(const float4*)&EP_o[(size_t)(s0 - WSZ + j) * C1LD + d4];
        *(float4*)&Pl[j * PST + d4] = v;
    }
    if (w < 44) {
        float2 fv = *(const float2*)&feat[(size_t)s * 88 + 2 * w];
        xl[q][2 * w] = fv.x; xl[q][2 * w + 1] = fv.y;
    }
    __syncthreads();

    // ---- phase A: onset attention ----
    {
        const int row = q + ((w < WIN) ? w : 0);
        const float* hrow = EH_o + (size_t)su * C1LD;   // uniform -> s_load
        const float* pb = &Pl[row * PST];
        float accr = 0.f;
#pragma unroll 8
        for (int d4 = 0; d4 < 32; d4++) {
            float4 p  = *(const float4*)(pb + d4 * 4);
            float4 hh = *(const float4*)(hrow + d4 * 4);
            float4 vv = *(const float4*)(vo + d4 * 4);
            accr += vv.x * __builtin_amdgcn_rcpf(__builtin_fmaf(hh.x, p.x, 1.f));
            accr += vv.y * __builtin_amdgcn_rcpf(__builtin_fmaf(hh.y, p.y, 1.f));
            accr += vv.z * __builtin_amdgcn_rcpf(__builtin_fmaf(hh.z, p.z, 1.f));
            accr += vv.w * __builtin_amdgcn_rcpf(__builtin_fmaf(hh.w, p.w, 1.f));
        }
        float eng = svp[0] - 2.f * accr;
        if (w >= WIN) eng = -1e30f;
        float mx = eng;
#pragma unroll
        for (int m = 32; m; m >>= 1) mx = fmaxf(mx, __shfl_xor(mx, m, 64));
        float ex = __expf(eng - mx);
        float sm = ex;
#pragma unroll
        for (int m = 32; m; m >>= 1) sm += __shfl_xor(sm, m, 64);
        float a = ex * __builtin_amdgcn_rcpf(sm);
        if (w < WIN) a_o[(size_t)s * WIN + w] = a;

        if (w < 44) {
            const int f = 2 * w;
            float2 bb = *(const float2*)&bl1[f];
            float acc0 = bb.x, acc1 = bb.y;
            const float* Rbase = Rm + (size_t)(s - WSZ) * C1LD + f;
            if (inner) {
#pragma unroll
                for (int ww = 0; ww < WIN; ww++) {
                    float aw = __uint_as_float(
                        __builtin_amdgcn_readlane(__float_as_uint(a), ww));
                    float2 rr = *(const float2*)(Rbase + (size_t)ww * C1LD);
                    acc0 += aw * rr.x; acc1 += aw * rr.y;
                }
            } else {
                for (int ww = 0; ww < WIN; ww++) {
                    int tg = t0 + q + ww - WSZ;
                    if ((unsigned)tg < (unsigned)TLEN) {
                        float aw = __uint_as_float(
                            __builtin_amdgcn_readlane(__float_as_uint(a), ww));
                        float2 rr = *(const float2*)(Rbase + (size_t)ww * C1LD);
                        acc0 += aw * rr.x; acc1 += aw * rr.y;
                    }
                }
            }
            float p0 = sigmoid_f(acc0), p1 = sigmoid_f(acc1);
            *(float2*)&onset[(size_t)s * OUTF + f] = make_float2(p0, p1);
            xl[q][88 + f] = p0; xl[q][89 + f] = p1;
        }
    }
    __syncthreads();   // all waves done with Pl (EP_o) and own xl complete

    // ---- stage EP_c (loads overlap the matvec below) ----
    for (int i = tid; i < 68 * 32; i += 512) {
        int j = i >> 5, d4 = (i & 31) * 4;
        int tg = t0 + j - WSZ;
        float4 v = {1.f, 1.f, 1.f, 1.f};
        if ((unsigned)tg < (unsigned)TLEN)
            v = *(const float4*)&EP_c[(size_t)(s0 - WSZ + j) * C1LD + d4];
        *(float4*)&Pl[j * PST + d4] = v;
    }

    // ---- phase B: matvec x[s] @ W2 -> EH_c, linx ----
    {
        float acc0 = bias2[w], acc1 = bias2[w + 64], acc2 = 0.f, acc3 = 0.f;
        const ushort_t* w0 = W2 + (size_t)w * 192;
        const ushort_t* w1 = W2 + (size_t)(w + 64) * 192;
        const ushort_t* w2 = W2 + (size_t)(w + 128) * 192;
        const ushort_t* w3 = W2 + (size_t)((w < 24) ? (w + 192) : 255) * 192;
#pragma unroll 11
        for (int c = 0; c < 22; c++) {
            float4 xa = *(const float4*)&xl[q][c * 8];
            float4 xb = *(const float4*)&xl[q][c * 8 + 4];
            acc0 += dot8(w0 + c * 8, xa, xb);
            acc1 += dot8(w1 + c * 8, xa, xb);
            acc2 += dot8(w2 + c * 8, xa, xb);
            acc3 += dot8(w3 + c * 8, xa, xb);
        }
        EHl[q][w]      = __expf(acc0 + acc0);
        EHl[q][w + 64] = __expf(acc1 + acc1);
        lxl[q][w] = acc2;
        if (w < 24) lxl[q][w + 64] = acc3;
    }
    __syncthreads();   // EP_c staged by all waves

    // ---- phase C: combine attention ----
    {
        const int row = q + ((w < WIN) ? w : 0);
        const float* hrow = &EHl[q][0];                // LDS broadcast
        const float* pb = &Pl[row * PST];
        float accr = 0.f;
#pragma unroll 8
        for (int d4 = 0; d4 < 32; d4++) {
            float4 p  = *(const float4*)(pb + d4 * 4);
            float4 hh = *(const float4*)(hrow + d4 * 4);
            float4 vv = *(const float4*)(vc + d4 * 4);
            accr += vv.x * __builtin_amdgcn_rcpf(__builtin_fmaf(hh.x, p.x, 1.f));
            accr += vv.y * __builtin_amdgcn_rcpf(__builtin_fmaf(hh.y, p.y, 1.f));
            accr += vv.z * __builtin_amdgcn_rcpf(__builtin_fmaf(hh.z, p.z, 1.f));
            accr += vv.w * __builtin_amdgcn_rcpf(__builtin_fmaf(hh.w, p.w, 1.f));
        }
        float eng = svp[1] - 2.f * accr;
        if (w >= WIN) eng = -1e30f;
        float mx = eng;
#pragma unroll
        for (int m = 32; m; m >>= 1) mx = fmaxf(mx, __shfl_xor(mx, m, 64));
        float ex = __expf(eng - mx);
        float sm = ex;
#pragma unroll
        for (int m = 32; m; m >>= 1) sm += __shfl_xor(sm, m, 64);
        float a = ex * __builtin_amdgcn_rcpf(sm);
        if (w < WIN) a_c[(size_t)s * WIN + w] = a;

        if (w < 44) {
            const int f = 2 * w;
            float2 bb = *(const float2*)&blc[f];
            float2 lx = *(const float2*)&lxl[q][f];
            float acc0 = bb.x + lx.x, acc1 = bb.y + lx.y;
            const float* Qbase = Qm + (size_t)(s - WSZ) * C1LD + f;
            if (inner) {
#pragma unroll
                for (int ww = 0; ww < WIN; ww++) {
                    float aw = __uint_as_float(
                        __builtin_amdgcn_readlane(__float_as_uint(a), ww));
                    float2 rr = *(const float2*)(Qbase + (size_t)ww * C1LD);
                    acc0 += aw * rr.x; acc1 += aw * rr.y;
                }
            } else {
                for (int ww = 0; ww < WIN; ww++) {
                    int tg = t0 + q + ww - WSZ;
                    if ((unsigned)tg < (unsigned)TLEN) {
                        float aw = __uint_as_float(
                            __builtin_amdgcn_readlane(__float_as_uint(a), ww));
                        float2 rr = *(const float2*)(Qbase + (size_t)ww * C1LD);
                        acc0 += aw * rr.x; acc1 += aw * rr.y;
                    }
                }
            }
            float p0 = sigmoid_f(acc0), p1 = sigmoid_f(acc1);
            *(float2*)&frame[(size_t)s * OUTF + f] = make_float2(p0, p1);
        }
    }
}

// ---------------------------------------------------------------------------
extern "C" void kernel_launch(void* const* d_in, const int* in_sizes, int n_in,
                              void* d_out, int out_size, void* d_ws, size_t ws_size,
                              hipStream_t stream)
{
    const float* spec = (const float*)d_in[0];
    const float* Wf   = (const float*)d_in[1];
    const float* bf_  = (const float*)d_in[2];
    const float* Wao  = (const float*)d_in[3];
    const float* bao  = (const float*)d_in[4];
    const float* vo   = (const float*)d_in[5];
    const float* Wl1  = (const float*)d_in[6];
    const float* bl1  = (const float*)d_in[7];
    const float* Wac  = (const float*)d_in[8];
    const float* bac  = (const float*)d_in[9];
    const float* vc   = (const float*)d_in[10];
    const float* Wlc  = (const float*)d_in[11];
    const float* blc  = (const float*)d_in[12];

    float* out  = (float*)d_out;
    float* out0 = out;                 // frame_pred [BT,88]
    float* out1 = out + 360448;        // a_frame    [BT,61]
    float* out2 = out + 610304;        // onset_pred [BT,88]
    float* out3 = out + 970752;        // a_onset    [BT,61]
    float* out4 = out + 1220608;       // feat_pred  [BT,88]

    float* ws = (float*)d_ws;
    float*    sv    = ws;                          // 2 (pad 16)
    float*    bias1 = ws + 16;                     // 704
    float*    bias2 = ws + 720;                    // 256
    ushort_t* B1b   = (ushort_t*)(ws + 976);       // 704*256 u16 = 90112 f
    ushort_t* B2b   = (ushort_t*)(ws + 91088);     // 256*192 u16 = 24576 f
    ushort_t* specB = (ushort_t*)(ws + 115664);    // 4096*256 u16 = 524288 f
    float*    C1    = ws + 639952;                 // 4096*560 (end 2,933,712)
    (void)ws_size; (void)in_sizes; (void)n_in; (void)out_size;

    // C1 cols [88,648) at stride 560; attn operands exp'd in gemm1 epilogue:
    float* h_o = C1;          // exp(2(h+bao))
    float* P_o = C1 + 128;    // exp(2p)
    float* P_c = C1 + 256;    // exp(2p)
    float* Rm  = C1 + 384;
    float* Qm  = C1 + 472;

    prep_kernel<<<PREP_BLOCKS, 256, 0, stream>>>(
        Wf, bf_, Wao, bao, Wl1, Wac, bac, Wlc, spec, vo, vc,
        B1b, B2b, specB, bias1, bias2, sv);

    gemm_mfma<1, 8, 3><<<dim3(NP1 / 64, 64), 256, 0, stream>>>(
        specB, 256, B1b, bias1, C1, C1LD, NC1, 88, 88, 472, out4);

    attn_fused<<<BT / 8, 512, 0, stream>>>(
        h_o, P_o, P_c, Rm, Qm, vo, vc, sv, bl1, blc, bias2, B2b,
        out4, out3, out2, out1, out0);
}

// Round 9
// 133.259 us; speedup vs baseline: 1.2915x; 1.2915x over previous
//
#include <hip/hip_runtime.h>

#define NBINS 229
#define OUTF  88
#define MODEL 128
#define WSZ   30
#define WIN   61
#define TLEN  1024
#define BT    4096

#define NC1 648      // gemm1 real cols
#define NP1 704      // gemm1 padded cols (11*64)
#define KP1 256      // gemm1 padded K (8*32); real 229
#define NC2 216      // gemm2 real cols
#define KP2 192      // gemm2 padded K (6*32); real 176

typedef short bf16x8 __attribute__((ext_vector_type(8)));
typedef float f32x4 __attribute__((ext_vector_type(4)));
typedef unsigned short ushort_t;

__device__ __forceinline__ float sigmoid_f(float x) {
    return __builtin_amdgcn_rcpf(1.f + __expf(-x));
}
__device__ __forceinline__ ushort_t f2bf(float f) {
    unsigned u = __float_as_uint(f);
    return (ushort_t)((u + 0x7fffu + ((u >> 16) & 1u)) >> 16);
}

// ---------------------------------------------------------------------------
// prep: build bf16 GEMM operands + fp32 biases + sv sums + xB k-pad zeros.
// B1b[n][k] (n-major, 704x256) column map (n):
//   [  0, 88) Wf[k][n]          [ 88,216) Wao[k][n-88]
//   [216,344) Wao[k+229][n-216] [344,472) Wac[k+176][n-344]
//   [472,560) Wl1[k][n-472]     [560,648) Wlc[k+176][n-560]
// B2b[n][k] (256x192): [0,128) Wac[k][n]; [128,216) Wlc[k][n-128]; pad 0
// specB[4096][256] bf16 row-major (k>=229 zero)
// xB[4096][192] bf16: cols 176..191 zeroed here
// bias1: [0,88)=bf, [88,216)=bao, else 0 ; bias2: [0,128)=bac, else 0
// sv[0]=sum(vo), sv[1]=sum(vc)
// ---------------------------------------------------------------------------
#define PREP_BLOCKS 2181

__global__ __launch_bounds__(256) void prep_kernel(
    const float* __restrict__ Wf,  const float* __restrict__ bfr,
    const float* __restrict__ Wao, const float* __restrict__ bao,
    const float* __restrict__ Wl1,
    const float* __restrict__ Wac, const float* __restrict__ bac,
    const float* __restrict__ Wlc,
    const float* __restrict__ spec,
    const float* __restrict__ vo, const float* __restrict__ vc,
    ushort_t* __restrict__ B1b, ushort_t* __restrict__ B2b,
    ushort_t* __restrict__ specB, ushort_t* __restrict__ xB,
    float* __restrict__ bias1, float* __restrict__ bias2,
    float* __restrict__ sv)
{
    __shared__ float red[4];
    const int b = blockIdx.x;
    if (b < 704) {                                  // B1b
        int idx = b * 256 + threadIdx.x;
        int n = idx >> 8, k = idx & 255;
        float v = 0.f;
        if (k < NBINS && n < NC1) {
            if (n < 88)       v = Wf[k * 88 + n];
            else if (n < 216) v = Wao[k * MODEL + (n - 88)];
            else if (n < 344) v = Wao[(k + NBINS) * MODEL + (n - 216)];
            else if (n < 472) v = Wac[(k + 176) * MODEL + (n - 344)];
            else if (n < 560) v = Wl1[k * 88 + (n - 472)];
            else              v = Wlc[(k + 176) * 88 + (n - 560)];
        }
        B1b[idx] = f2bf(v);
    } else if (b < 896) {                           // B2b
        int idx = (b - 704) * 256 + threadIdx.x;
        int n = idx / 192, k = idx - n * 192;
        float v = 0.f;
        if (k < 176 && n < NC2)
            v = (n < 128) ? Wac[k * MODEL + n] : Wlc[k * 88 + (n - 128)];
        B2b[idx] = f2bf(v);
    } else if (b < 1920) {                          // specB, 4 elems/thread
        int idx = (b - 896) * 256 + threadIdx.x;
        int r = idx >> 6, k4 = (idx & 63) * 4;
        const float* sp = spec + (size_t)r * NBINS;
        ushort4 o;
        o.x = (k4 + 0 < NBINS) ? f2bf(sp[k4 + 0]) : (ushort_t)0;
        o.y = (k4 + 1 < NBINS) ? f2bf(sp[k4 + 1]) : (ushort_t)0;
        o.z = (k4 + 2 < NBINS) ? f2bf(sp[k4 + 2]) : (ushort_t)0;
        o.w = (k4 + 3 < NBINS) ? f2bf(sp[k4 + 3]) : (ushort_t)0;
        *(ushort4*)&specB[(size_t)r * 256 + k4] = o;
    } else if (b < 2176) {                          // xB pad cols 176..191
        int idx = (b - 1920) * 256 + threadIdx.x;
        int r = idx >> 4, c = 176 + (idx & 15);
        xB[(size_t)r * 192 + c] = 0;
    } else if (b < 2180) {                          // biases
        int idx = (b - 2176) * 256 + threadIdx.x;
        if (idx < 704)
            bias1[idx] = (idx < 88) ? bfr[idx] : (idx < 216 ? bao[idx - 88] : 0.f);
        else if (idx < 960) {
            int n = idx - 704;
            bias2[n] = (n < 128) ? bac[n] : 0.f;
        }
    } else {                                        // sv sums
        int wid = threadIdx.x >> 6, lane = threadIdx.x & 63;
        const float* vp = (wid < 2) ? vo : vc;
        float val = vp[(wid & 1) * 64 + lane];
#pragma unroll
        for (int m = 32; m; m >>= 1) val += __shfl_xor(val, m, 64);
        if (lane == 0) red[wid] = val;
        __syncthreads();
        if (threadIdx.x == 0) {
            sv[0] = red[0] + red[1];
            sv[1] = red[2] + red[3];
        }
    }
}

// ---------------------------------------------------------------------------
// MFMA bf16 GEMM, no LDS; wave tile 16m x 64n, block 64m x 64n (4 waves).
// XCD swizzle: e=flat&7 -> rows [512e,512e+512) on XCD e (RTS=3).
// MODE 0 (gemm1) epilogue by column n:
//   n<88: feat fp32 + xB bf16 | 88..216: EHo=exp(2v) fp32 | 216..344: EPo bf16
//   344..472: EPc bf16 (both exp'd) | 472..560: Rb bf16 | 560..648: Qb bf16
// MODE 1 (gemm2): C2 fp32; n<128 -> exp(2v) (EH_c), else plain (linx).
// ---------------------------------------------------------------------------
template<int KITER, int RTS, int MODE>
__global__ __launch_bounds__(256) void gemm_mfma(
    const ushort_t* __restrict__ Ab, int lka,
    const ushort_t* __restrict__ Bb,
    const float* __restrict__ bias, int Nc,
    float* __restrict__ f0, ushort_t* __restrict__ u0,
    float* __restrict__ f1, ushort_t* __restrict__ u1,
    ushort_t* __restrict__ u2, ushort_t* __restrict__ u3,
    ushort_t* __restrict__ u4)
{
    const int tid = threadIdx.x;
    const int wv = tid >> 6, ln = tid & 63;
    const int l15 = ln & 15, qd = ln >> 4;
    const int flat = blockIdx.y * gridDim.x + blockIdx.x;
    const int e = flat & 7, kf = flat >> 3;
    const int rb = (e * (1 << RTS) + (kf & ((1 << RTS) - 1))) * 64;
    const int cb = (kf >> RTS) * 64;
    const int lkb = KITER * 32;

    const ushort_t* ap = Ab + (size_t)(rb + wv * 16 + l15) * lka + qd * 8;
    const ushort_t* bp[4];
#pragma unroll
    for (int nt = 0; nt < 4; nt++)
        bp[nt] = Bb + (size_t)(cb + nt * 16 + l15) * lkb + qd * 8;

    f32x4 acc[4];
#pragma unroll
    for (int nt = 0; nt < 4; nt++) acc[nt] = (f32x4){0.f, 0.f, 0.f, 0.f};

    bf16x8 af = *(const bf16x8*)ap, bfv[4];
#pragma unroll
    for (int nt = 0; nt < 4; nt++) bfv[nt] = *(const bf16x8*)bp[nt];

    for (int it = 0; it < KITER; it++) {
        bf16x8 an, bn[4];
        const int nk = (it + 1 < KITER) ? (it + 1) * 32 : 0;
        an = *(const bf16x8*)(ap + nk);
#pragma unroll
        for (int nt = 0; nt < 4; nt++) bn[nt] = *(const bf16x8*)(bp[nt] + nk);
#pragma unroll
        for (int nt = 0; nt < 4; nt++)
            acc[nt] = __builtin_amdgcn_mfma_f32_16x16x32_bf16(
                af, bfv[nt], acc[nt], 0, 0, 0);
        af = an;
#pragma unroll
        for (int nt = 0; nt < 4; nt++) bfv[nt] = bn[nt];
    }

    const int mbase = rb + wv * 16 + qd * 4;
#pragma unroll
    for (int nt = 0; nt < 4; nt++) {
        const int n = cb + nt * 16 + l15;
        if (n < Nc) {
            const float bn = bias[n];
#pragma unroll
            for (int r = 0; r < 4; r++) {
                const int m = mbase + r;
                float val = acc[nt][r] + bn;
                if (MODE == 0) {
                    if (n < 88) {
                        f0[(size_t)m * 88 + n] = val;            // feat
                        u0[(size_t)m * 192 + n] = f2bf(val);     // xB
                    } else if (n < 216) {
                        f1[(size_t)m * 128 + (n - 88)] = __expf(val + val);
                    } else if (n < 344) {
                        u1[(size_t)m * 128 + (n - 216)] = f2bf(__expf(val + val));
                    } else if (n < 472) {
                        u2[(size_t)m * 128 + (n - 344)] = f2bf(__expf(val + val));
                    } else if (n < 560) {
                        u3[(size_t)m * 96 + (n - 472)] = f2bf(val);
                    } else {
                        u4[(size_t)m * 96 + (n - 560)] = f2bf(val);
                    }
                } else {
                    f0[(size_t)m * 216 + n] = (n < 128) ? __expf(val + val) : val;
                }
            }
        }
    }
}

// ---------------------------------------------------------------------------
// Attention v8: one wave per position, 8 per 512-thread block, XCD-swizzled.
// EP bf16 in LDS (stride 136 ushorts, pad rows = bf16(1.0) = exp(0));
// R/Q bf16 in LDS (stride 96, pad rows = 0 -> no window masking needed);
// EH fp32 + v fp32 via wave-uniform s_loads.
// e[w] = sv - 2*sum_d v[d]*rcp(EH[d]*EP[w][d] + 1); in-wave softmax;
// weighted sum from LDS via v_readlane.
// ---------------------------------------------------------------------------
#define EPST 136
#define RST  96

__global__ __launch_bounds__(512) void attn_v8(
    const float* __restrict__ EH_all, int hs,
    const ushort_t* __restrict__ EPb,
    const ushort_t* __restrict__ Rb,
    const float* __restrict__ vvec, const float* __restrict__ svp,
    const float* __restrict__ pred_bias,
    const float* __restrict__ base, int bs,
    float* __restrict__ a_out, float* __restrict__ pred_out,
    ushort_t* __restrict__ xb)
{
    __shared__ ushort_t Pl[68 * EPST];   // 18,496 B
    __shared__ ushort_t Rl[68 * RST];    // 13,056 B

    const int tid = threadIdx.x;
    const int s0 = ((blockIdx.x & 7) * 64 + (blockIdx.x >> 3)) * 8;
    const int t0 = s0 & (TLEN - 1);

    // stage EP (68 rows x 128 bf16): pad = bf16(1.0)
    for (int i = tid; i < 68 * 16; i += 512) {
        int j = i >> 4, c = (i & 15) * 8;
        int tg = t0 + j - WSZ;
        uint4 v = {0x3f803f80u, 0x3f803f80u, 0x3f803f80u, 0x3f803f80u};
        if ((unsigned)tg < (unsigned)TLEN)
            v = *(const uint4*)&EPb[(size_t)(s0 - WSZ + j) * 128 + c];
        *(uint4*)&Pl[j * EPST + c] = v;
    }
    // stage R/Q (68 rows x 96 bf16): pad = 0 (OOB windows contribute a*0)
    for (int i = tid; i < 68 * 12; i += 512) {
        int j = i / 12, c = (i - j * 12) * 8;
        int tg = t0 + j - WSZ;
        uint4 v = {0u, 0u, 0u, 0u};
        if ((unsigned)tg < (unsigned)TLEN)
            v = *(const uint4*)&Rb[(size_t)(s0 - WSZ + j) * 96 + c];
        *(uint4*)&Rl[j * RST + c] = v;
    }
    __syncthreads();

    const int q = tid >> 6;
    const int w = tid & 63;
    const int s = s0 + q;
    const int su = __builtin_amdgcn_readfirstlane(s);
    const int row = q + ((w < WIN) ? w : 0);
    const ushort_t* pb = &Pl[row * EPST];
    const float* hrow = EH_all + (size_t)su * hs;   // uniform -> s_load
    const float sv = svp[0];

    float accr = 0.f;
#pragma unroll
    for (int d8 = 0; d8 < 16; d8++) {
        uint4 pv = *(const uint4*)(pb + d8 * 8);
        const float* hp = hrow + d8 * 8;
        const float* vp = vvec + d8 * 8;
        float p0 = __uint_as_float(pv.x << 16);
        float p1 = __uint_as_float(pv.x & 0xffff0000u);
        float p2 = __uint_as_float(pv.y << 16);
        float p3 = __uint_as_float(pv.y & 0xffff0000u);
        float p4 = __uint_as_float(pv.z << 16);
        float p5 = __uint_as_float(pv.z & 0xffff0000u);
        float p6 = __uint_as_float(pv.w << 16);
        float p7 = __uint_as_float(pv.w & 0xffff0000u);
        accr += vp[0] * __builtin_amdgcn_rcpf(__builtin_fmaf(hp[0], p0, 1.f));
        accr += vp[1] * __builtin_amdgcn_rcpf(__builtin_fmaf(hp[1], p1, 1.f));
        accr += vp[2] * __builtin_amdgcn_rcpf(__builtin_fmaf(hp[2], p2, 1.f));
        accr += vp[3] * __builtin_amdgcn_rcpf(__builtin_fmaf(hp[3], p3, 1.f));
        accr += vp[4] * __builtin_amdgcn_rcpf(__builtin_fmaf(hp[4], p4, 1.f));
        accr += vp[5] * __builtin_amdgcn_rcpf(__builtin_fmaf(hp[5], p5, 1.f));
        accr += vp[6] * __builtin_amdgcn_rcpf(__builtin_fmaf(hp[6], p6, 1.f));
        accr += vp[7] * __builtin_amdgcn_rcpf(__builtin_fmaf(hp[7], p7, 1.f));
    }
    float eng = sv - 2.f * accr;
    if (w >= WIN) eng = -1e30f;

    float mx = eng;
#pragma unroll
    for (int m = 32; m; m >>= 1) mx = fmaxf(mx, __shfl_xor(mx, m, 64));
    float ex = __expf(eng - mx);
    float sm = ex;
#pragma unroll
    for (int m = 32; m; m >>= 1) sm += __shfl_xor(sm, m, 64);
    float a = ex * __builtin_amdgcn_rcpf(sm);
    if (w < WIN) a_out[(size_t)s * WIN + w] = a;

    if (w < 44) {
        const int f = 2 * w;
        float acc0 = pred_bias[f], acc1 = pred_bias[f + 1];
        if (base) {
            acc0 += base[(size_t)s * bs + f];
            acc1 += base[(size_t)s * bs + f + 1];
        }
        const ushort_t* rr0 = &Rl[q * RST + f];
#pragma unroll
        for (int ww = 0; ww < WIN; ww++) {
            float aw = __uint_as_float(
                __builtin_amdgcn_readlane(__float_as_uint(a), ww));
            unsigned u = *(const unsigned*)(rr0 + ww * RST);
            acc0 += aw * __uint_as_float(u << 16);
            acc1 += aw * __uint_as_float(u & 0xffff0000u);
        }
        float p0 = sigmoid_f(acc0), p1 = sigmoid_f(acc1);
        *(float2*)&pred_out[(size_t)s * OUTF + f] = make_float2(p0, p1);
        if (xb) {
            ushort2 o; o.x = f2bf(p0); o.y = f2bf(p1);
            *(ushort2*)&xb[(size_t)s * 192 + 88 + f] = o;
        }
    }
}

// ---------------------------------------------------------------------------
extern "C" void kernel_launch(void* const* d_in, const int* in_sizes, int n_in,
                              void* d_out, int out_size, void* d_ws, size_t ws_size,
                              hipStream_t stream)
{
    const float* spec = (const float*)d_in[0];
    const float* Wf   = (const float*)d_in[1];
    const float* bf_  = (const float*)d_in[2];
    const float* Wao  = (const float*)d_in[3];
    const float* bao  = (const float*)d_in[4];
    const float* vo   = (const float*)d_in[5];
    const float* Wl1  = (const float*)d_in[6];
    const float* bl1  = (const float*)d_in[7];
    const float* Wac  = (const float*)d_in[8];
    const float* bac  = (const float*)d_in[9];
    const float* vc   = (const float*)d_in[10];
    const float* Wlc  = (const float*)d_in[11];
    const float* blc  = (const float*)d_in[12];

    float* out  = (float*)d_out;
    float* out0 = out;                 // frame_pred [BT,88]
    float* out1 = out + 360448;        // a_frame    [BT,61]
    float* out2 = out + 610304;        // onset_pred [BT,88]
    float* out3 = out + 970752;        // a_onset    [BT,61]
    float* out4 = out + 1220608;       // feat_pred  [BT,88]

    float* ws = (float*)d_ws;
    float*    sv    = ws;                          // 2 (pad 16)
    float*    bias1 = ws + 16;                     // 704
    float*    bias2 = ws + 720;                    // 256
    ushort_t* B1b   = (ushort_t*)(ws + 976);       // 704*256 u16
    ushort_t* B2b   = (ushort_t*)(ws + 91088);     // 256*192 u16
    ushort_t* specB = (ushort_t*)(ws + 115664);    // 4096*256 u16
    ushort_t* xB    = (ushort_t*)(ws + 639952);    // 4096*192 u16
    float*    EHo   = ws + 1033168;                // 4096*128 fp32
    ushort_t* EPo   = (ushort_t*)(ws + 1557456);   // 4096*128 u16
    ushort_t* EPc   = (ushort_t*)(ws + 1819600);   // 4096*128 u16
    ushort_t* Rb    = (ushort_t*)(ws + 2081744);   // 4096*96 u16
    ushort_t* Qb    = (ushort_t*)(ws + 2278352);   // 4096*96 u16
    float*    C2    = ws + 2474960;                // 4096*216 fp32 (end ~13.4MB)
    (void)ws_size; (void)in_sizes; (void)n_in; (void)out_size;

    prep_kernel<<<PREP_BLOCKS, 256, 0, stream>>>(
        Wf, bf_, Wao, bao, Wl1, Wac, bac, Wlc, spec, vo, vc,
        B1b, B2b, specB, xB, bias1, bias2, sv);

    gemm_mfma<8, 3, 0><<<dim3(NP1 / 64, 64), 256, 0, stream>>>(
        specB, 256, B1b, bias1, NC1, out4, xB, EHo, EPo, EPc, Rb, Qb);

    attn_v8<<<BT / 8, 512, 0, stream>>>(
        EHo, 128, EPo, Rb, vo, sv, bl1, nullptr, 0, out3, out2, xB);

    gemm_mfma<6, 3, 1><<<dim3(4, 64), 256, 0, stream>>>(
        xB, 192, B2b, bias2, NC2, C2, nullptr, nullptr, nullptr,
        nullptr, nullptr, nullptr);

    attn_v8<<<BT / 8, 512, 0, stream>>>(
        C2, 216, EPc, Qb, vc, sv + 1, blc, C2 + 128, 216, out1, out0, nullptr);
}